// Round 1
// baseline (779.469 us; speedup 1.0000x reference)
//
#include <hip/hip_runtime.h>
#include <math.h>

// Problem constants (fixed by reference setup_inputs).
constexpr int kB  = 2048;   // batch
constexpr int kV  = 50000;  // vocab / senses
constexpr int kD  = 512;    // embed dim
constexpr int kK  = 5;      // top-k
constexpr int kNT = 256;    // threads per block (4 waves)
constexpr int kWaves = kNT / 64;

// Total order on (value desc, index asc) — matches jax.lax.top_k tie-break.
__device__ __forceinline__ bool key_before(float va, int ia, float vb, int ib) {
    return (va > vb) || ((va == vb) && (ia < ib));
}

__global__ __launch_bounds__(kNT) void topk_attn_kernel(
        const float* __restrict__ sp_z,     // [B,V]
        const float* __restrict__ sp_w,     // [V,D]
        const float* __restrict__ encoded,  // [B,D]
        float* __restrict__ out,            // [B,D]
        float* __restrict__ attn_out,       // [B,K]
        float* __restrict__ idx_out)        // [B,K], float-encoded ints
{
    const int row  = blockIdx.x;
    const int tid  = threadIdx.x;
    const int lane = tid & 63;
    const int wave = tid >> 6;

    __shared__ float s_val[kWaves][kK];
    __shared__ int   s_idx[kWaves][kK];
    __shared__ float s_dot[kWaves][kK];

    // ---- Phase 1: streaming top-5 over this row of sp_z -------------------
    // Scalar registers only (NO runtime-indexed arrays -> no scratch).
    float v0 = -INFINITY, v1 = -INFINITY, v2 = -INFINITY, v3 = -INFINITY, v4 = -INFINITY;
    int   i0 = 0x7fffffff, i1 = 0x7fffffff, i2 = 0x7fffffff, i3 = 0x7fffffff, i4 = 0x7fffffff;

    // Stable insert of (x,id) into the descending 5-list; fully predicated,
    // all compile-time register names.
    auto insert = [&](float x, int id) {
        if (!key_before(x, id, v4, i4)) return;   // common fast reject
        const bool b3 = key_before(v3, i3, x, id);
        const bool b2 = key_before(v2, i2, x, id);
        const bool b1 = key_before(v1, i1, x, id);
        const bool b0 = key_before(v0, i0, x, id);
        // slot_i = b_i ? old_i : (b_{i-1} ? x : old_{i-1}); update high->low so
        // each slot reads not-yet-updated neighbors.
        v4 = b3 ? x  : v3;              i4 = b3 ? id : i3;
        v3 = b3 ? v3 : (b2 ? x  : v2);  i3 = b3 ? i3 : (b2 ? id : i2);
        v2 = b2 ? v2 : (b1 ? x  : v1);  i2 = b2 ? i2 : (b1 ? id : i1);
        v1 = b1 ? v1 : (b0 ? x  : v0);  i1 = b1 ? i1 : (b0 ? id : i0);
        v0 = b0 ? v0 : x;               i0 = b0 ? i0 : id;
    };

    const float4* z4 = reinterpret_cast<const float4*>(sp_z + (size_t)row * kV);
    constexpr int n4 = kV / 4;   // 12500, exact
    for (int i = tid; i < n4; i += kNT) {
        const float4 q = z4[i];
        const int base = i << 2;
        insert(q.x, base);
        insert(q.y, base + 1);
        insert(q.z, base + 2);
        insert(q.w, base + 3);
    }

    // Wave64 butterfly merge: snapshot partner's list, stream-insert it.
    // Symmetric, so all 64 lanes converge to the wave's top-5.
#pragma unroll
    for (int off = 1; off < 64; off <<= 1) {
        const float ov0 = __shfl_xor(v0, off); const int oi0 = __shfl_xor(i0, off);
        const float ov1 = __shfl_xor(v1, off); const int oi1 = __shfl_xor(i1, off);
        const float ov2 = __shfl_xor(v2, off); const int oi2 = __shfl_xor(i2, off);
        const float ov3 = __shfl_xor(v3, off); const int oi3 = __shfl_xor(i3, off);
        const float ov4 = __shfl_xor(v4, off); const int oi4 = __shfl_xor(i4, off);
        insert(ov0, oi0); insert(ov1, oi1); insert(ov2, oi2);
        insert(ov3, oi3); insert(ov4, oi4);
    }

    // Cross-wave merge via LDS (4 lists of 5).
    if (lane == 0) {
        s_val[wave][0] = v0; s_val[wave][1] = v1; s_val[wave][2] = v2;
        s_val[wave][3] = v3; s_val[wave][4] = v4;
        s_idx[wave][0] = i0; s_idx[wave][1] = i1; s_idx[wave][2] = i2;
        s_idx[wave][3] = i3; s_idx[wave][4] = i4;
    }
    __syncthreads();
#pragma unroll
    for (int w = 0; w < kWaves; ++w) {
        if (w == wave) continue;   // wave-uniform branch, fully unrolled
        insert(s_val[w][0], s_idx[w][0]);
        insert(s_val[w][1], s_idx[w][1]);
        insert(s_val[w][2], s_idx[w][2]);
        insert(s_val[w][3], s_idx[w][3]);
        insert(s_val[w][4], s_idx[w][4]);
    }
    // Every thread now holds the identical final top-5 (v0..v4 / i0..i4).

    // ---- Phase 2: gather + attention + weighted sum -----------------------
    // Each thread owns 2 consecutive columns (float2, coalesced 8B/lane).
    const float2 e = reinterpret_cast<const float2*>(encoded + (size_t)row * kD)[tid];

    int idxs[kK] = {i0, i1, i2, i3, i4};   // constant-indexed below (unrolled)
    float wx[kK], wy[kK], p[kK];
#pragma unroll
    for (int k = 0; k < kK; ++k) {
        const float2 wv =
            reinterpret_cast<const float2*>(sp_w + (size_t)idxs[k] * kD)[tid];
        wx[k] = wv.x; wy[k] = wv.y;
        p[k]  = wv.x * e.x + wv.y * e.y;
    }
    // Wave-reduce the 5 partial dot products.
#pragma unroll
    for (int k = 0; k < kK; ++k) {
#pragma unroll
        for (int off = 32; off >= 1; off >>= 1) p[k] += __shfl_xor(p[k], off);
    }
    if (lane == 0) {
#pragma unroll
        for (int k = 0; k < kK; ++k) s_dot[wave][k] = p[k];
    }
    __syncthreads();

    float s[kK];
#pragma unroll
    for (int k = 0; k < kK; ++k)
        s[k] = s_dot[0][k] + s_dot[1][k] + s_dot[2][k] + s_dot[3][k];

    // Softmax over 5 (replicated in every thread; all identical).
    const float m = fmaxf(fmaxf(fmaxf(s[0], s[1]), fmaxf(s[2], s[3])), s[4]);
    float a[kK]; float asum = 0.f;
#pragma unroll
    for (int k = 0; k < kK; ++k) { a[k] = expf(s[k] - m); asum += a[k]; }
    const float inv = 1.0f / asum;
#pragma unroll
    for (int k = 0; k < kK; ++k) a[k] *= inv;

    float ox = 0.f, oy = 0.f;
#pragma unroll
    for (int k = 0; k < kK; ++k) { ox += a[k] * wx[k]; oy += a[k] * wy[k]; }
    reinterpret_cast<float2*>(out + (size_t)row * kD)[tid] = make_float2(ox, oy);

    if (tid == 0) {
#pragma unroll
        for (int k = 0; k < kK; ++k) {
            attn_out[(size_t)row * kK + k] = a[k];
            idx_out[(size_t)row * kK + k] = (float)idxs[k];
        }
    }
}

extern "C" void kernel_launch(void* const* d_in, const int* in_sizes, int n_in,
                              void* d_out, int out_size, void* d_ws, size_t ws_size,
                              hipStream_t stream) {
    const float* sp_z    = (const float*)d_in[0];
    const float* sp_w    = (const float*)d_in[1];
    const float* encoded = (const float*)d_in[2];

    float* out  = (float*)d_out;                     // [B,D]
    float* attn = out  + (size_t)kB * kD;            // [B,K]
    float* idxf = attn + (size_t)kB * kK;            // [B,K]

    topk_attn_kernel<<<kB, kNT, 0, stream>>>(sp_z, sp_w, encoded, out, attn, idxf);
}

// Round 2
// 608.715 us; speedup vs baseline: 1.2805x; 1.2805x over previous
//
#include <hip/hip_runtime.h>
#include <math.h>

// Problem constants (fixed by reference setup_inputs).
constexpr int kB  = 2048;   // batch
constexpr int kV  = 50000;  // vocab / senses
constexpr int kD  = 512;    // embed dim
constexpr int kK  = 5;      // top-k
constexpr int kNT = 256;    // threads per block (4 waves)
constexpr int kWaves = kNT / 64;
constexpr int kQuads = kV / 4;        // 12500 float4 per row
constexpr int kChunkQuads = 1024;     // first 4096 elements give the threshold
constexpr int kCap = 1024;            // candidate queue capacity (mean ~61 used)

// Total order on (value desc, index asc) — matches jax.lax.top_k tie-break.
__device__ __forceinline__ bool key_before(float va, int ia, float vb, int ib) {
    return (va > vb) || ((va == vb) && (ia < ib));
}

// Descending top-5 list in scalar registers (no runtime indexing -> no scratch).
struct Top5 {
    float v0, v1, v2, v3, v4;
    int   i0, i1, i2, i3, i4;
    __device__ __forceinline__ void init() {
        v0 = v1 = v2 = v3 = v4 = -INFINITY;
        i0 = i1 = i2 = i3 = i4 = 0x7fffffff;
    }
    __device__ __forceinline__ void insert(float x, int id) {
        if (!key_before(x, id, v4, i4)) return;   // fast reject
        const bool b3 = key_before(v3, i3, x, id);
        const bool b2 = key_before(v2, i2, x, id);
        const bool b1 = key_before(v1, i1, x, id);
        const bool b0 = key_before(v0, i0, x, id);
        v4 = b3 ? x  : v3;              i4 = b3 ? id : i3;
        v3 = b3 ? v3 : (b2 ? x  : v2);  i3 = b3 ? i3 : (b2 ? id : i2);
        v2 = b2 ? v2 : (b1 ? x  : v1);  i2 = b2 ? i2 : (b1 ? id : i1);
        v1 = b1 ? v1 : (b0 ? x  : v0);  i1 = b1 ? i1 : (b0 ? id : i0);
        v0 = b0 ? v0 : x;               i0 = b0 ? i0 : id;
    }
    __device__ __forceinline__ void merge_shfl(int off) {
        const float a0 = __shfl_xor(v0, off), a1 = __shfl_xor(v1, off),
                    a2 = __shfl_xor(v2, off), a3 = __shfl_xor(v3, off),
                    a4 = __shfl_xor(v4, off);
        const int   c0 = __shfl_xor(i0, off), c1 = __shfl_xor(i1, off),
                    c2 = __shfl_xor(i2, off), c3 = __shfl_xor(i3, off),
                    c4 = __shfl_xor(i4, off);
        insert(a0, c0); insert(a1, c1); insert(a2, c2); insert(a3, c3); insert(a4, c4);
    }
};

__global__ __launch_bounds__(kNT) void topk_attn_kernel(
        const float* __restrict__ sp_z,     // [B,V]
        const float* __restrict__ sp_w,     // [V,D]
        const float* __restrict__ encoded,  // [B,D]
        float* __restrict__ out,            // [B,D]
        float* __restrict__ attn_out,       // [B,K]
        float* __restrict__ idx_out)        // [B,K], float-encoded ints
{
    const int row  = blockIdx.x;
    const int tid  = threadIdx.x;
    const int lane = tid & 63;
    const int wave = tid >> 6;

    __shared__ float s_val[kWaves][kK];
    __shared__ int   s_idx[kWaves][kK];
    __shared__ float s_bufv[kCap];
    __shared__ int   s_bufi[kCap];
    __shared__ int   s_cnt;
    __shared__ float s_dot[kWaves][kK];

    const float4* z4 = reinterpret_cast<const float4*>(sp_z + (size_t)row * kV);

    // ---- Phase A: exact top-5 of the first 4096 elements ------------------
    Top5 t; t.init();
#pragma unroll
    for (int it = 0; it < kChunkQuads / kNT; ++it) {   // 4 iterations
        const int i = it * kNT + tid;
        const float4 q = z4[i];
        const int base = i << 2;
        t.insert(q.x, base); t.insert(q.y, base + 1);
        t.insert(q.z, base + 2); t.insert(q.w, base + 3);
    }
#pragma unroll
    for (int off = 1; off < 64; off <<= 1) t.merge_shfl(off);
    if (lane == 0) {
        s_val[wave][0] = t.v0; s_val[wave][1] = t.v1; s_val[wave][2] = t.v2;
        s_val[wave][3] = t.v3; s_val[wave][4] = t.v4;
        s_idx[wave][0] = t.i0; s_idx[wave][1] = t.i1; s_idx[wave][2] = t.i2;
        s_idx[wave][3] = t.i3; s_idx[wave][4] = t.i4;
    }
    if (tid == 0) s_cnt = kK;   // slots 0..4 reserved for the chunk top-5
    __syncthreads();
#pragma unroll
    for (int w = 0; w < kWaves; ++w) {
        if (w == wave) continue;
        t.insert(s_val[w][0], s_idx[w][0]); t.insert(s_val[w][1], s_idx[w][1]);
        t.insert(s_val[w][2], s_idx[w][2]); t.insert(s_val[w][3], s_idx[w][3]);
        t.insert(s_val[w][4], s_idx[w][4]);
    }
    // All threads now hold the identical chunk top-5; its 5th value is a
    // provably-safe filter threshold: row ⊇ chunk ⇒ x5(row) ≥ x5(chunk).
    const float t0 = t.v4;
    if (tid == 0) {
        s_bufv[0] = t.v0; s_bufv[1] = t.v1; s_bufv[2] = t.v2;
        s_bufv[3] = t.v3; s_bufv[4] = t.v4;
        s_bufi[0] = t.i0; s_bufi[1] = t.i1; s_bufi[2] = t.i2;
        s_bufi[3] = t.i3; s_bufi[4] = t.i4;
    }

    // ---- Phase B: filtered stream over the remaining 45904 elements -------
    // Common path per float4: 3 v_max + 1 cmp; survivors (~56/row) queue to LDS.
#pragma unroll 2
    for (int i = kChunkQuads + tid; i < kQuads; i += kNT) {
        const float4 q = z4[i];
        const float m = fmaxf(fmaxf(q.x, q.y), fmaxf(q.z, q.w));
        if (m >= t0) {                                  // rare slow path
            const int base = i << 2;
            if (q.x >= t0) { int p = atomicAdd(&s_cnt, 1); if (p < kCap) { s_bufv[p] = q.x; s_bufi[p] = base;     } }
            if (q.y >= t0) { int p = atomicAdd(&s_cnt, 1); if (p < kCap) { s_bufv[p] = q.y; s_bufi[p] = base + 1; } }
            if (q.z >= t0) { int p = atomicAdd(&s_cnt, 1); if (p < kCap) { s_bufv[p] = q.z; s_bufi[p] = base + 2; } }
            if (q.w >= t0) { int p = atomicAdd(&s_cnt, 1); if (p < kCap) { s_bufv[p] = q.w; s_bufi[p] = base + 3; } }
        }
    }
    __syncthreads();
    const int cnt = s_cnt;   // block-uniform after the barrier

    // ---- Phase C: exact top-5 of the candidates ---------------------------
    Top5 f; f.init();
    if (cnt <= kCap) {
        for (int p = tid; p < cnt; p += kNT) f.insert(s_bufv[p], s_bufi[p]);
    } else {
        // Queue overflow (only possible with massive ties): exact full rescan.
        for (int i = tid; i < kQuads; i += kNT) {
            const float4 q = z4[i];
            const int base = i << 2;
            f.insert(q.x, base); f.insert(q.y, base + 1);
            f.insert(q.z, base + 2); f.insert(q.w, base + 3);
        }
    }
#pragma unroll
    for (int off = 1; off < 64; off <<= 1) f.merge_shfl(off);
    __syncthreads();   // everyone done with s_val chunk contents
    if (lane == 0) {
        s_val[wave][0] = f.v0; s_val[wave][1] = f.v1; s_val[wave][2] = f.v2;
        s_val[wave][3] = f.v3; s_val[wave][4] = f.v4;
        s_idx[wave][0] = f.i0; s_idx[wave][1] = f.i1; s_idx[wave][2] = f.i2;
        s_idx[wave][3] = f.i3; s_idx[wave][4] = f.i4;
    }
    __syncthreads();
#pragma unroll
    for (int w = 0; w < kWaves; ++w) {
        if (w == wave) continue;
        f.insert(s_val[w][0], s_idx[w][0]); f.insert(s_val[w][1], s_idx[w][1]);
        f.insert(s_val[w][2], s_idx[w][2]); f.insert(s_val[w][3], s_idx[w][3]);
        f.insert(s_val[w][4], s_idx[w][4]);
    }
    // Every thread holds the identical final top-5 (f.v*, f.i*).

    // ---- Phase D: gather + attention + weighted sum -----------------------
    const float2 e = reinterpret_cast<const float2*>(encoded + (size_t)row * kD)[tid];

    int idxs[kK] = {f.i0, f.i1, f.i2, f.i3, f.i4};   // constant-indexed (unrolled)
    float wx[kK], wy[kK], p[kK];
#pragma unroll
    for (int k = 0; k < kK; ++k) {
        const float2 wv =
            reinterpret_cast<const float2*>(sp_w + (size_t)idxs[k] * kD)[tid];
        wx[k] = wv.x; wy[k] = wv.y;
        p[k]  = wv.x * e.x + wv.y * e.y;
    }
#pragma unroll
    for (int k = 0; k < kK; ++k) {
#pragma unroll
        for (int off = 32; off >= 1; off >>= 1) p[k] += __shfl_xor(p[k], off);
    }
    if (lane == 0) {
#pragma unroll
        for (int k = 0; k < kK; ++k) s_dot[wave][k] = p[k];
    }
    __syncthreads();

    float s[kK];
#pragma unroll
    for (int k = 0; k < kK; ++k)
        s[k] = s_dot[0][k] + s_dot[1][k] + s_dot[2][k] + s_dot[3][k];

    const float m = fmaxf(fmaxf(fmaxf(s[0], s[1]), fmaxf(s[2], s[3])), s[4]);
    float a[kK]; float asum = 0.f;
#pragma unroll
    for (int k = 0; k < kK; ++k) { a[k] = expf(s[k] - m); asum += a[k]; }
    const float inv = 1.0f / asum;
#pragma unroll
    for (int k = 0; k < kK; ++k) a[k] *= inv;

    float ox = 0.f, oy = 0.f;
#pragma unroll
    for (int k = 0; k < kK; ++k) { ox += a[k] * wx[k]; oy += a[k] * wy[k]; }
    reinterpret_cast<float2*>(out + (size_t)row * kD)[tid] = make_float2(ox, oy);

    if (tid == 0) {
#pragma unroll
        for (int k = 0; k < kK; ++k) {
            attn_out[(size_t)row * kK + k] = a[k];
            idx_out[(size_t)row * kK + k] = (float)idxs[k];
        }
    }
}

extern "C" void kernel_launch(void* const* d_in, const int* in_sizes, int n_in,
                              void* d_out, int out_size, void* d_ws, size_t ws_size,
                              hipStream_t stream) {
    const float* sp_z    = (const float*)d_in[0];
    const float* sp_w    = (const float*)d_in[1];
    const float* encoded = (const float*)d_in[2];

    float* out  = (float*)d_out;                     // [B,D]
    float* attn = out  + (size_t)kB * kD;            // [B,K]
    float* idxf = attn + (size_t)kB * kK;            // [B,K]

    topk_attn_kernel<<<kB, kNT, 0, stream>>>(sp_z, sp_w, encoded, out, attn, idxf);
}